// Round 14
// baseline (85.997 us; speedup 1.0000x reference)
//
#include <hip/hip_runtime.h>
#include <utility>

#define D_DIM 256
#define WID   33
#define CEN   16
#define RSTR  32                   // rows per block (512*32 = N exactly)
#define WINW  (RSTR + WID - 1)     // 64-row x window
#define PRE   41                   // upfront prefetch; row k issues W[41+k]

// R13 (84.9us) post-mortem: wave = [97-load burst][pure compute, 0 outstanding]
// -> avg outstanding-bytes too low, read BW capped ~3.2 TB/s. Fix: manual
// 9-row-lookahead pipeline (row k issues load W[41+k], first used at row k+9),
// order pinned with sched_barrier(0) so the backend can't sink loads to their
// consumers (R8-proven failure mode). x index CLAMPED (ref semantics: clip x,
// zero weight) -> single code path, no per-load selects; boundary blocks zero
// invalid weight lanes. XCD swizzle: each XCD = one batch, consecutive strips.

__device__ __forceinline__ float rdlane(float v, int l) {
    return __uint_as_float(__builtin_amdgcn_readlane(__float_as_uint(v), l));
}

__device__ __forceinline__ int clampN(int p, int N) {
    return p < 0 ? 0 : (p >= N ? N - 1 : p);
}

template <size_t... Is>
__device__ __forceinline__ void load_head(float (&W)[WINW],
                                          const float* __restrict__ xb,
                                          int base, int N,
                                          std::index_sequence<Is...>) {
    ((W[Is] = xb[(size_t)clampN(base + (int)Is, N) * D_DIM]), ...);
}

template <size_t... Rs>
__device__ __forceinline__ void load_w(float (&wv)[RSTR],
                                       const float* __restrict__ smb,
                                       int n0, int minl,
                                       std::index_sequence<Rs...>) {
    ((wv[Rs] = smb[(size_t)(n0 + (int)Rs) * WID + minl]), ...);
}

template <size_t... Rs>
__device__ __forceinline__ void zero_bad_w(float (&wv)[RSTR], int n0, int lane,
                                           int N, std::index_sequence<Rs...>) {
    ((wv[Rs] = ((unsigned)(n0 + (int)Rs - CEN + lane) < (unsigned)N)
                   ? wv[Rs] : 0.0f),
     ...);
}

template <int K, size_t... Is>
__device__ __forceinline__ float dot_row(const float (&W)[WINW], float wrow,
                                         std::index_sequence<Is...>) {
    float acc[4] = {0.f, 0.f, 0.f, 0.f};
    ((acc[Is & 3] = fmaf(W[K + (int)Is], rdlane(wrow, (int)Is), acc[Is & 3])),
     ...);
    return (acc[0] + acc[1]) + (acc[2] + acc[3]);
}

template <int K>
__device__ __forceinline__ void row_step(float (&W)[WINW], const float (&wv)[RSTR],
                                         float szv, float* __restrict__ ob,
                                         const float* __restrict__ xb,
                                         int base, int N) {
    if constexpr (PRE + K < WINW) {        // pipelined load, 9-row lookahead
        const int p = base + PRE + K;      // >= 25, only upper clamp needed
        W[PRE + K] = xb[(size_t)(p >= N ? N - 1 : p) * D_DIM];
    }
    __builtin_amdgcn_sched_barrier(0);     // pin: no sinking across rows
    const float s   = dot_row<K>(W, wv[K], std::make_index_sequence<WID>{});
    const float inv = __builtin_amdgcn_rcpf(fmaxf(rdlane(szv, K), 1e-6f));
    ob[(size_t)K * D_DIM] = s * inv;
}

template <size_t... Ks>
__device__ __forceinline__ void all_rows(float (&W)[WINW], const float (&wv)[RSTR],
                                         float szv, float* __restrict__ ob,
                                         const float* __restrict__ xb,
                                         int base, int N,
                                         std::index_sequence<Ks...>) {
    (row_step<(int)Ks>(W, wv, szv, ob, xb, base, N), ...);
}

__global__ __launch_bounds__(256, 4) void local_enc_kernel(
    const float* __restrict__ x, const float* __restrict__ sizev,
    const float* __restrict__ sm, float* __restrict__ out, int N) {
    // XCD swizzle: XCD k owns batch k, strips consecutive -> halo L2-local
    const int bid   = blockIdx.x;
    const int swz   = (bid & 7) * 512 + (bid >> 3);
    const int strip = swz & 511;
    const int b     = swz >> 9;
    const int n0    = strip * RSTR;
    const int tid   = threadIdx.x;
    const int lane  = tid & 63;

    const size_t bN = (size_t)b * (size_t)N;
    const float* __restrict__ xb  = x   + bN * D_DIM + tid;
    float*       __restrict__ ob  = out + (bN + (size_t)n0) * D_DIM + tid;
    const float* __restrict__ smb = sm    + bN * WID;
    const float* __restrict__ szb = sizev + bN;

    // issue order: sizes, weights, window head — dot 0 never drains the tail
    const int minl = (lane < WID) ? lane : (WID - 1);
    const float szv = szb[(n0 + minl < N) ? (n0 + minl) : (N - 1)];

    float wv[RSTR];
    load_w(wv, smb, n0, minl, std::make_index_sequence<RSTR>{});
    if (n0 < CEN || n0 + RSTR - 1 + CEN >= N)            // 16 of 4096 blocks
        zero_bad_w(wv, n0, lane, N, std::make_index_sequence<RSTR>{});

    const int base = n0 - CEN;
    float W[WINW];
    load_head(W, xb, base, N, std::make_index_sequence<PRE>{});

    __builtin_amdgcn_sched_barrier(0);
    all_rows(W, wv, szv, ob, xb, base, N, std::make_index_sequence<RSTR>{});
}

extern "C" void kernel_launch(void* const* d_in, const int* in_sizes, int n_in,
                              void* d_out, int out_size, void* d_ws, size_t ws_size,
                              hipStream_t stream) {
    const float* x  = (const float*)d_in[0];
    const float* sz = (const float*)d_in[1];
    const float* sm = (const float*)d_in[2];
    float* out = (float*)d_out;

    const int B = 8;
    const int N = 16384;

    dim3 grid((N / RSTR) * B, 1, 1);   // 4096 blocks, XCD-swizzled
    dim3 block(D_DIM, 1, 1);
    local_enc_kernel<<<grid, block, 0, stream>>>(x, sz, sm, out, N);
}